// Round 12
// baseline (932.792 us; speedup 1.0000x reference)
//
#include <hip/hip_runtime.h>
#include <hip/hip_bf16.h>
#include <math.h>

#define NN 50000
#define EE 800000
#define FIN 128
#define HIDN 128
#define HD 32
#define FEATD 268
#define K1 288           // GEMM1 K padded to 9*32
#define TN2 64

typedef __bf16 bf16x8 __attribute__((ext_vector_type(8)));
typedef float  f32x4  __attribute__((ext_vector_type(4)));

#define MFMA(a, b, c) __builtin_amdgcn_mfma_f32_16x16x32_bf16((a), (b), (c), 0, 0, 0)

__device__ __forceinline__ float silu_f(float x) {
    return x / (1.0f + __expf(-x));
}

// Transpose + bf16-convert all weights into ws each launch (deterministic).
__global__ void wconv_kernel(const float* __restrict__ eW1, const float* __restrict__ eW2,
                             const float* __restrict__ cW1, const float* __restrict__ nW1,
                             const float* __restrict__ nW2,
                             __bf16* __restrict__ eW1t, __bf16* __restrict__ eW2t,
                             __bf16* __restrict__ cW1t, __bf16* __restrict__ nW1t,
                             __bf16* __restrict__ nW2t)
{
    const int i = blockIdx.x * 256 + threadIdx.x;
    if (i < 4 * 32 * K1) {
        const int hh = i / (32 * K1), rs = i % (32 * K1), d = rs / K1, k = rs % K1;
        const float v = (k < FEATD) ? eW1[(size_t)hh * FEATD * HD + (size_t)k * HD + d] : 0.f;
        eW1t[i] = (__bf16)v;
    }
    if (i < 4 * HD * HD) {
        const int hh = i / (HD * HD), rs = i % (HD * HD), d = rs / HD, k = rs % HD;
        eW2t[i] = (__bf16)eW2[(size_t)hh * HD * HD + (size_t)k * HD + d];
    }
    if (i < HIDN * HIDN) {
        const int o = i / HIDN, k = i % HIDN;
        cW1t[i] = (__bf16)cW1[(size_t)k * HIDN + o];
    }
    if (i < HIDN * (2 * FIN)) {
        const int o = i / (2 * FIN), k = i % (2 * FIN);
        nW1t[i] = (__bf16)nW1[(size_t)k * HIDN + o];
    }
    if (i < FIN * HIDN) {
        const int o = i / HIDN, k = i % HIDN;
        nW2t[i] = (__bf16)nW2[(size_t)k * FIN + o];
    }
}

// Convert h (f32 [NN][128]) -> bf16, stored in the LOWER 256B of each 512B
// h_out row (upper 256B holds the packed-bf16 agg accumulator).
__global__ __launch_bounds__(256) void hconv_kernel(const float* __restrict__ h,
                                                    float* __restrict__ houtbase)
{
    const int i = blockIdx.x * 256 + threadIdx.x;   // one per 8 elems
    if (i >= NN * FIN / 8) return;
    const int row = i >> 4;          // 16 threads per row
    const int c8  = i & 15;          // 8-elem chunk within row
    const float4* src = (const float4*)(h + (size_t)row * FIN + c8 * 8);
    float4 a = src[0], b = src[1];
    bf16x8 v = { (__bf16)a.x, (__bf16)a.y, (__bf16)a.z, (__bf16)a.w,
                 (__bf16)b.x, (__bf16)b.y, (__bf16)b.z, (__bf16)b.w };
    *(bf16x8*)((char*)houtbase + (size_t)row * 512 + c8 * 16) = v;
}

// WAVE-AUTONOMOUS edge kernel: 256 threads = 4 independent waves, each wave
// owns 16 edges end-to-end (all 4 heads). NO __syncthreads anywhere — all
// LDS regions are per-wave private; same-wave lgkmcnt ordering suffices.
// A-fragments loaded once into registers, reused across heads. LN fully
// in-register (shuffle row-sums). Indices/cdiff in lane regs via __shfl.
__global__ __launch_bounds__(256) void edge_kernel(
    const float* __restrict__ coord,
    const int* __restrict__ ei,
    const __bf16* __restrict__ eW1t, const float* __restrict__ eb1,
    const __bf16* __restrict__ eW2t, const float* __restrict__ eb2,
    const float* __restrict__ ln_g, const float* __restrict__ ln_b,
    const __bf16* __restrict__ cW1t, const float* __restrict__ cb1,
    const float* __restrict__ cW2,
    float* __restrict__ houtbase, float* __restrict__ coord_out)
{
    __shared__ __align__(16) __bf16 geomS[4][16][40];    // 5,120B
    __shared__ __align__(16) __bf16 hidS[4][16][136];    // 17,408B (hid -> efs reuse)

    const int t    = threadIdx.x;
    const int w    = t >> 6;
    const int lane = t & 63;
    const int lr   = lane & 15;
    const int lg   = lane >> 4;
    const int ebase = blockIdx.x * 64 + w * 16;

    __bf16 (*geomW)[40]  = geomS[w];
    __bf16 (*hidW)[136]  = hidS[w];

    // ---------------- Phase A: geometry + indices (lanes 0..15, 1 edge each) ----------------
    int rI = 0, cI = 0;
    float cdx = 0.f, cdy = 0.f, cdz = 0.f;
    if (lane < 16) {
        rI = ei[ebase + lane];
        cI = ei[EE + ebase + lane];
        const float cix = coord[(size_t)rI*3+0], ciy = coord[(size_t)rI*3+1], ciz = coord[(size_t)rI*3+2];
        const float ckx = coord[(size_t)cI*3+0], cky = coord[(size_t)cI*3+1], ckz = coord[(size_t)cI*3+2];
        cdx = cix-ckx; cdy = ciy-cky; cdz = ciz-ckz;
        const float radial = cdx*cdx + cdy*cdy + cdz*cdz;
        const float dist   = sqrtf(radial);
        const float dotv   = cix*ckx + ciy*cky + ciz*ckz;
        const float ia = 1.0f / (dist + 1e-8f);
        float ax = cdx*ia, ay = cdy*ia, az = cdz*ia;
        const float cpx = ciy*ckz - ciz*cky;
        const float cpy = ciz*ckx - cix*ckz;
        const float cpz = cix*cky - ciy*ckx;
        const float cpn = sqrtf(cpx*cpx + cpy*cpy + cpz*cpz);
        const float ib = 1.0f / (cpn + 1e-8f);
        float bx = cpx*ib, by = cpy*ib, bz = cpz*ib;
        float cx = ay*bz - az*by;
        float cy = az*bx - ax*bz;
        float cz = ax*by - ay*bx;
        const float na = sqrtf(ax*ax + ay*ay + az*az);
        const float nb = sqrtf(bx*bx + by*by + bz*bz);
        const float nc = sqrtf(cx*cx + cy*cy + cz*cz);
        if (na < 1e-6f || nb < 1e-6f || nc < 1e-6f) {
            ax=1.f; bx=0.f; cx=0.f;
            ay=0.f; by=1.f; cy=0.f;
            az=0.f; bz=0.f; cz=1.f;
        }
        geomW[lane][0]=(__bf16)radial; geomW[lane][1]=(__bf16)dist; geomW[lane][2]=(__bf16)dotv;
        geomW[lane][3]=(__bf16)ax; geomW[lane][4]=(__bf16)bx; geomW[lane][5]=(__bf16)cx;
        geomW[lane][6]=(__bf16)ay; geomW[lane][7]=(__bf16)by; geomW[lane][8]=(__bf16)cy;
        geomW[lane][9]=(__bf16)az; geomW[lane][10]=(__bf16)bz; geomW[lane][11]=(__bf16)cz;
        #pragma unroll
        for (int k = 12; k < 32; k++) geomW[lane][k] = (__bf16)0.f;
    }
    const int rB = __shfl(rI, lr);     // row-node of this lane's edge (lr)
    const int cB = __shfl(cI, lr);     // col-node

    // ---------------- Load all GEMM1 A-fragments into registers (shared across heads) ----------------
    bf16x8 aF[9];
    {
        const char* pr = (const char*)houtbase + (size_t)rB * 512 + lg * 16;
        const char* pc = (const char*)houtbase + (size_t)cB * 512 + lg * 16;
        #pragma unroll
        for (int ks = 0; ks < 4; ks++) aF[ks]     = *(const bf16x8*)(pr + ks * 64);
        #pragma unroll
        for (int ks = 0; ks < 4; ks++) aF[4 + ks] = *(const bf16x8*)(pc + ks * 64);
        aF[8] = *(const bf16x8*)(&geomW[lr][lg * 8]);   // same-wave lgkmcnt ordering
    }

    const f32x4 z4 = { 0.f, 0.f, 0.f, 0.f };

    // ---------------- GEMM1: all 4 heads, A reused from regs -> hidW (C/D layout) ----------------
    #pragma unroll
    for (int hh = 0; hh < 4; hh++) {
        f32x4 acc0 = z4, acc1 = z4;
        const __bf16* W1 = eW1t + (size_t)hh * 32 * K1;
        #pragma unroll
        for (int ks = 0; ks < 9; ks++) {
            const int kof = ks * 32 + lg * 8;
            bf16x8 b0 = *(const bf16x8*)(W1 + (size_t)lr * K1 + kof);
            bf16x8 b1 = *(const bf16x8*)(W1 + (size_t)(16 + lr) * K1 + kof);
            acc0 = MFMA(aF[ks], b0, acc0);
            acc1 = MFMA(aF[ks], b1, acc1);
        }
        const float b1a = eb1[hh * HD + lr];
        const float b1b = eb1[hh * HD + 16 + lr];
        #pragma unroll
        for (int r = 0; r < 4; r++) {
            const int erow = lg * 4 + r;
            hidW[erow][hh * 32 + lr]      = (__bf16)silu_f(acc0[r] + b1a);
            hidW[erow][hh * 32 + 16 + lr] = (__bf16)silu_f(acc1[r] + b1b);
        }
    }

    // ---------------- GEMM2: all 4 heads -> val in regs ----------------
    float val[4][2][4];
    #pragma unroll
    for (int hh = 0; hh < 4; hh++) {
        f32x4 acc0 = z4, acc1 = z4;
        const __bf16* W2 = eW2t + (size_t)hh * HD * HD;
        const int kof2 = lg * 8;
        bf16x8 b20 = *(const bf16x8*)(W2 + (size_t)lr * HD + kof2);
        bf16x8 b21 = *(const bf16x8*)(W2 + (size_t)(16 + lr) * HD + kof2);
        bf16x8 a = *(const bf16x8*)(&hidW[lr][hh * 32 + kof2]);
        acc0 = MFMA(a, b20, acc0);
        acc1 = MFMA(a, b21, acc1);
        const float b2a = eb2[hh * HD + lr];
        const float b2b = eb2[hh * HD + 16 + lr];
        #pragma unroll
        for (int r = 0; r < 4; r++) {
            val[hh][0][r] = acc0[r] + b2a;
            val[hh][1][r] = acc1[r] + b2b;
        }
    }

    // ---------------- LayerNorm fully in registers (shuffle row-sums) ----------------
    {
        float gg[4][2], bb[4][2];
        #pragma unroll
        for (int hh = 0; hh < 4; hh++) {
            gg[hh][0] = ln_g[hh * 32 + lr];      bb[hh][0] = ln_b[hh * 32 + lr];
            gg[hh][1] = ln_g[hh * 32 + 16 + lr]; bb[hh][1] = ln_b[hh * 32 + 16 + lr];
        }
        #pragma unroll
        for (int r = 0; r < 4; r++) {
            float s = 0.f, s2 = 0.f;
            #pragma unroll
            for (int hh = 0; hh < 4; hh++) {
                s  += val[hh][0][r] + val[hh][1][r];
                s2 += val[hh][0][r] * val[hh][0][r] + val[hh][1][r] * val[hh][1][r];
            }
            s  += __shfl_xor(s, 1);  s2 += __shfl_xor(s2, 1);
            s  += __shfl_xor(s, 2);  s2 += __shfl_xor(s2, 2);
            s  += __shfl_xor(s, 4);  s2 += __shfl_xor(s2, 4);
            s  += __shfl_xor(s, 8);  s2 += __shfl_xor(s2, 8);
            const float mu   = s * (1.f / 128.f);
            const float var  = s2 * (1.f / 128.f) - mu * mu;
            const float rstd = rsqrtf(var + 1e-5f);
            const int erow = lg * 4 + r;
            #pragma unroll
            for (int hh = 0; hh < 4; hh++) {
                hidW[erow][hh * 32 + lr]      = (__bf16)((val[hh][0][r] - mu) * rstd * gg[hh][0] + bb[hh][0]);
                hidW[erow][hh * 32 + 16 + lr] = (__bf16)((val[hh][1][r] - mu) * rstd * gg[hh][1] + bb[hh][1]);
            }
        }
    }
    // hidW now holds LN'd edge_feat (bf16) -- the "efs" buffer.

    // ---------------- agg scatter: packed 2xbf16 atomics (issue early, fire-and-forget) ----------------
    {
        const int eA = lane >> 2;                 // edge 0..15
        const int rA = __shfl(rI, eA);
        char* dst = (char*)houtbase + (size_t)rA * 512 + 256;
        #pragma unroll
        for (int j = 0; j < 16; j++) {
            const int p = (lane & 3) + 4 * j;     // pair 0..63
            __hip_bfloat162 pk = *(__hip_bfloat162*)((char*)&hidW[eA][0] + p * 4);
            unsafeAtomicAdd((__hip_bfloat162*)(dst + p * 4), pk);
        }
    }

    // ---------------- GEMM3: efs @ cW1t^T (128 outs) -> silu -> *cW2 -> w -> coord atomics ----------------
    {
        bf16x8 a3[4];
        #pragma unroll
        for (int ks = 0; ks < 4; ks++)
            a3[ks] = *(const bf16x8*)(&hidW[lr][ks * 32 + lg * 8]);
        float pe[4] = {0.f, 0.f, 0.f, 0.f};
        #pragma unroll
        for (int cg = 0; cg < 8; cg++) {
            f32x4 acc3 = z4;
            const __bf16* W3 = cW1t + (size_t)(cg * 16 + lr) * HIDN;
            #pragma unroll
            for (int ks = 0; ks < 4; ks++) {
                bf16x8 b = *(const bf16x8*)(W3 + ks * 32 + lg * 8);
                acc3 = MFMA(a3[ks], b, acc3);
            }
            const int c = cg * 16 + lr;
            const float cb = cb1[c];
            const float cw = cW2[c];
            #pragma unroll
            for (int r = 0; r < 4; r++)
                pe[r] += silu_f(acc3[r] + cb) * cw;
        }
        #pragma unroll
        for (int d = 1; d < 16; d <<= 1) {
            #pragma unroll
            for (int r = 0; r < 4; r++) pe[r] += __shfl_xor(pe[r], d);
        }
        // broadcast cdiff / row for the 4 edges this lg-group covers
        float cde[4][3]; int rEe[4];
        #pragma unroll
        for (int r = 0; r < 4; r++) {
            const int e = lg * 4 + r;
            rEe[r]    = __shfl(rI, e);
            cde[r][0] = __shfl(cdx, e);
            cde[r][1] = __shfl(cdy, e);
            cde[r][2] = __shfl(cdz, e);
        }
        if (lr == 0) {
            #pragma unroll
            for (int r = 0; r < 4; r++) {
                atomicAdd(&coord_out[(size_t)rEe[r]*3+0], cde[r][0] * pe[r]);
                atomicAdd(&coord_out[(size_t)rEe[r]*3+1], cde[r][1] * pe[r]);
                atomicAdd(&coord_out[(size_t)rEe[r]*3+2], cde[r][2] * pe[r]);
            }
        }
    }
}

// 512 threads = 8 waves. Reads the full 512B h_out row = [hB bf16[128] | agg bf16[128]]
// = the 256-dim bf16 node-MLP input, then overwrites the row with final f32 h_out.
__global__ __launch_bounds__(512) void node_kernel(
    const float* __restrict__ h,
    const __bf16* __restrict__ nW1t, const float* __restrict__ nb1,
    const __bf16* __restrict__ nW2t, const float* __restrict__ nb2,
    float* __restrict__ h_out)
{
    __shared__ __align__(16) __bf16 featsN[TN2][264];   // [64][256+8]
    __shared__ __align__(16) __bf16 hidN[TN2][136];     // [64][128+8]

    const int t  = threadIdx.x;
    const int n0 = blockIdx.x * TN2;

    // ---------------- Phase 0: stage [hB | agg] row directly ----------------
    {
        const int n = t >> 3;
        const int q = t & 7;
        const int nid = n0 + n;
        const bool ok = nid < NN;
        const uint4* rowp = (const uint4*)((const char*)h_out + (size_t)nid * 512);
        #pragma unroll
        for (int j = 0; j < 4; j++) {
            const int w4 = q * 4 + j;                  // uint4 index 0..31
            uint4 u = ok ? rowp[w4] : make_uint4(0u, 0u, 0u, 0u);
            *(uint4*)&featsN[n][w4 * 8] = u;
        }
    }
    __syncthreads();

    const int wv2  = t >> 6;
    const int hh2  = wv2 >> 1;        // output col-group (0..3)
    const int mh   = wv2 & 1;         // node-half
    const int lane = t & 63;
    const int lr   = lane & 15;
    const int lg   = lane >> 4;

    const f32x4 z4 = { 0.f, 0.f, 0.f, 0.f };

    // ---------------- GEMM1n (MFMA): featsN[64x256] @ nW1t^T -> silu -> hidN ----------------
    {
        f32x4 acc[2][2];
        #pragma unroll
        for (int mti = 0; mti < 2; mti++) { acc[mti][0] = z4; acc[mti][1] = z4; }
        const __bf16* W1 = nW1t + (size_t)hh2 * 32 * 256;
        #pragma unroll
        for (int ks = 0; ks < 8; ks++) {
            const int kof = ks * 32 + lg * 8;
            bf16x8 b0 = *(const bf16x8*)(W1 + (size_t)lr * 256 + kof);
            bf16x8 b1 = *(const bf16x8*)(W1 + (size_t)(16 + lr) * 256 + kof);
            #pragma unroll
            for (int mti = 0; mti < 2; mti++) {
                bf16x8 a = *(const bf16x8*)(&featsN[(mh * 2 + mti) * 16 + lr][kof]);
                acc[mti][0] = MFMA(a, b0, acc[mti][0]);
                acc[mti][1] = MFMA(a, b1, acc[mti][1]);
            }
        }
        const float b1a = nb1[hh2 * 32 + lr];
        const float b1b = nb1[hh2 * 32 + 16 + lr];
        #pragma unroll
        for (int mti = 0; mti < 2; mti++) {
            #pragma unroll
            for (int r = 0; r < 4; r++) {
                const int erow = (mh * 2 + mti) * 16 + lg * 4 + r;
                hidN[erow][hh2 * 32 + lr]      = (__bf16)silu_f(acc[mti][0][r] + b1a);
                hidN[erow][hh2 * 32 + 16 + lr] = (__bf16)silu_f(acc[mti][1][r] + b1b);
            }
        }
    }
    __syncthreads();

    // ---------------- GEMM2n (MFMA): hidN[64x128] @ nW2t^T + nb2 + h -> h_out ----------------
    {
        f32x4 acc2[2][2];
        #pragma unroll
        for (int mti = 0; mti < 2; mti++) { acc2[mti][0] = z4; acc2[mti][1] = z4; }
        const __bf16* W2 = nW2t + (size_t)hh2 * 32 * 128;
        #pragma unroll
        for (int ks = 0; ks < 4; ks++) {
            const int kof = ks * 32 + lg * 8;
            bf16x8 b0 = *(const bf16x8*)(W2 + (size_t)lr * 128 + kof);
            bf16x8 b1 = *(const bf16x8*)(W2 + (size_t)(16 + lr) * 128 + kof);
            #pragma unroll
            for (int mti = 0; mti < 2; mti++) {
                bf16x8 a = *(const bf16x8*)(&hidN[(mh * 2 + mti) * 16 + lr][kof]);
                acc2[mti][0] = MFMA(a, b0, acc2[mti][0]);
                acc2[mti][1] = MFMA(a, b1, acc2[mti][1]);
            }
        }
        const float b2a = nb2[hh2 * 32 + lr];
        const float b2b = nb2[hh2 * 32 + 16 + lr];
        const int c0 = hh2 * 32 + lr, c1 = c0 + 16;
        #pragma unroll
        for (int mti = 0; mti < 2; mti++) {
            #pragma unroll
            for (int r = 0; r < 4; r++) {
                const int erow = (mh * 2 + mti) * 16 + lg * 4 + r;
                const int nid  = n0 + erow;
                if (nid < NN) {
                    h_out[(size_t)nid * FIN + c0] = h[(size_t)nid * FIN + c0] + acc2[mti][0][r] + b2a;
                    h_out[(size_t)nid * FIN + c1] = h[(size_t)nid * FIN + c1] + acc2[mti][1][r] + b2b;
                }
            }
        }
    }
}

extern "C" void kernel_launch(void* const* d_in, const int* in_sizes, int n_in,
                              void* d_out, int out_size, void* d_ws, size_t ws_size,
                              hipStream_t stream)
{
    (void)in_sizes; (void)n_in; (void)out_size; (void)ws_size;
    const float* h     = (const float*)d_in[0];
    const float* coord = (const float*)d_in[1];
    const int*   ei    = (const int*)d_in[2];
    const float* eW1   = (const float*)d_in[3];
    const float* eb1   = (const float*)d_in[4];
    const float* eW2   = (const float*)d_in[5];
    const float* eb2   = (const float*)d_in[6];
    const float* ln_g  = (const float*)d_in[7];
    const float* ln_b  = (const float*)d_in[8];
    const float* nW1   = (const float*)d_in[9];
    const float* nb1   = (const float*)d_in[10];
    const float* nW2   = (const float*)d_in[11];
    const float* nb2   = (const float*)d_in[12];
    const float* cW1   = (const float*)d_in[13];
    const float* cb1   = (const float*)d_in[14];
    const float* cW2   = (const float*)d_in[15];

    float* h_out     = (float*)d_out;
    float* coord_out = h_out + (size_t)NN * FIN;

    // bf16 transposed weights in ws
    __bf16* eW1t = (__bf16*)d_ws;               // 36864 elems
    __bf16* eW2t = eW1t + 4 * 32 * K1;          // 4096
    __bf16* cW1t = eW2t + 4 * HD * HD;          // 16384
    __bf16* nW1t = cW1t + HIDN * HIDN;          // 32768
    __bf16* nW2t = nW1t + HIDN * (2 * FIN);     // 16384  (total ~213KB of ws)

    // h_out row layout during edge phase: [hB bf16[128] | packed-bf16 agg[128]]
    hipMemsetAsync(h_out, 0, (size_t)NN * FIN * sizeof(float), stream);
    hipMemcpyAsync(coord_out, coord, (size_t)NN * 3 * sizeof(float),
                   hipMemcpyDeviceToDevice, stream);
    wconv_kernel<<<(4 * 32 * K1 + 255) / 256, 256, 0, stream>>>(
        eW1, eW2, cW1, nW1, nW2, eW1t, eW2t, cW1t, nW1t, nW2t);
    hconv_kernel<<<(NN * FIN / 8 + 255) / 256, 256, 0, stream>>>(h, h_out);

    edge_kernel<<<EE / 64, 256, 0, stream>>>(coord, ei, eW1t, eb1, eW2t, eb2,
                                             ln_g, ln_b, cW1t, cb1, cW2,
                                             h_out, coord_out);
    node_kernel<<<(NN + TN2 - 1) / TN2, 512, 0, stream>>>(h, nW1t, nb1, nW2t, nb2, h_out);
}

// Round 13
// 406.790 us; speedup vs baseline: 2.2931x; 2.2931x over previous
//
#include <hip/hip_runtime.h>
#include <hip/hip_bf16.h>
#include <math.h>

#define NN 50000
#define EE 800000
#define FIN 128
#define HIDN 128
#define HD 32
#define FEATD 268
#define K1 288           // GEMM1 K padded to 9*32
#define KP1 296          // featsB LDS row stride (bf16 elems)
#define TE 32
#define TN2 64

typedef __bf16 bf16x8 __attribute__((ext_vector_type(8)));
typedef float  f32x4  __attribute__((ext_vector_type(4)));

#define MFMA(a, b, c) __builtin_amdgcn_mfma_f32_16x16x32_bf16((a), (b), (c), 0, 0, 0)

__device__ __forceinline__ float silu_f(float x) {
    return x / (1.0f + __expf(-x));
}

// Transpose + bf16-convert all weights into ws each launch (deterministic).
__global__ void wconv_kernel(const float* __restrict__ eW1, const float* __restrict__ eW2,
                             const float* __restrict__ cW1, const float* __restrict__ nW1,
                             const float* __restrict__ nW2,
                             __bf16* __restrict__ eW1t, __bf16* __restrict__ eW2t,
                             __bf16* __restrict__ cW1t, __bf16* __restrict__ nW1t,
                             __bf16* __restrict__ nW2t)
{
    const int i = blockIdx.x * 256 + threadIdx.x;
    if (i < 4 * 32 * K1) {
        const int hh = i / (32 * K1), rs = i % (32 * K1), d = rs / K1, k = rs % K1;
        const float v = (k < FEATD) ? eW1[(size_t)hh * FEATD * HD + (size_t)k * HD + d] : 0.f;
        eW1t[i] = (__bf16)v;
    }
    if (i < 4 * HD * HD) {
        const int hh = i / (HD * HD), rs = i % (HD * HD), d = rs / HD, k = rs % HD;
        eW2t[i] = (__bf16)eW2[(size_t)hh * HD * HD + (size_t)k * HD + d];
    }
    if (i < HIDN * HIDN) {
        const int o = i / HIDN, k = i % HIDN;
        cW1t[i] = (__bf16)cW1[(size_t)k * HIDN + o];
    }
    if (i < HIDN * (2 * FIN)) {
        const int o = i / (2 * FIN), k = i % (2 * FIN);
        nW1t[i] = (__bf16)nW1[(size_t)k * HIDN + o];
    }
    if (i < FIN * HIDN) {
        const int o = i / HIDN, k = i % HIDN;
        nW2t[i] = (__bf16)nW2[(size_t)k * FIN + o];
    }
}

// Convert h (f32 [NN][128]) -> bf16, stored in the LOWER 256B of each 512B
// h_out row (upper 256B holds the packed-bf16 agg accumulator).
__global__ __launch_bounds__(256) void hconv_kernel(const float* __restrict__ h,
                                                    float* __restrict__ houtbase)
{
    const int i = blockIdx.x * 256 + threadIdx.x;   // one per 8 elems
    if (i >= NN * FIN / 8) return;
    const int row = i >> 4;          // 16 threads per row
    const int c8  = i & 15;          // 8-elem chunk within row
    const float4* src = (const float4*)(h + (size_t)row * FIN + c8 * 8);
    float4 a = src[0], b = src[1];
    bf16x8 v = { (__bf16)a.x, (__bf16)a.y, (__bf16)a.z, (__bf16)a.w,
                 (__bf16)b.x, (__bf16)b.y, (__bf16)b.z, (__bf16)b.w };
    *(bf16x8*)((char*)houtbase + (size_t)row * 512 + c8 * 16) = v;
}

// TE=32, 256 threads = 4 waves, wave = head. Same phase structure, LDS
// layouts, and coalesced scatter as the Round-10 kernel, but half the tile:
// LDS ~29.8KB -> 5 blocks/CU, so 5 independent barrier groups per CU.
__global__ __launch_bounds__(256) void edge_kernel(
    const float* __restrict__ coord,
    const int* __restrict__ ei,
    const __bf16* __restrict__ eW1t, const float* __restrict__ eb1,
    const __bf16* __restrict__ eW2t, const float* __restrict__ eb2,
    const float* __restrict__ ln_g, const float* __restrict__ ln_b,
    const __bf16* __restrict__ cW1t, const float* __restrict__ cb1,
    const float* __restrict__ cW2,
    float* __restrict__ houtbase, float* __restrict__ coord_out)
{
    // smemA: featsB bf16[32][296] (18,944B) -> later efs f32[32][132] (16,896B)
    // smemB: hidB bf16[4][32][40] (10,240B) -> later efsB bf16[32][136] (8,704B)
    __shared__ __align__(16) unsigned char smemA[TE * KP1 * 2];
    __shared__ __align__(16) unsigned char smemB[4 * TE * 40 * 2];
    __shared__ float cdiff[TE][3];
    __shared__ int   rowlds[TE];
    __shared__ float wsum[TE];

    __bf16 (*featsB)[KP1] = (__bf16 (*)[KP1])smemA;
    float  (*efs)[132]    = (float  (*)[132])smemA;
    __bf16 (*efsB)[136]   = (__bf16 (*)[136])smemB;

    const int t  = threadIdx.x;
    const int e0 = blockIdx.x * TE;

    if (t < TE) wsum[t] = 0.f;

    // ---------------- Phase 0: gather hB (bf16) + geometry into featsB ----------------
    {
        const int e = t >> 3;        // edge 0..31 (8 threads/edge)
        const int q = t & 7;
        const int r = ei[e0 + e];
        const int c = ei[EE + e0 + e];
        #pragma unroll
        for (int j = 0; j < 2; j++) {
            const int c16 = q + 8 * j;   // 16B-chunk index 0..15
            uint4 vr = *(const uint4*)((const char*)houtbase + (size_t)r * 512 + c16 * 16);
            *(uint4*)&featsB[e][c16 * 8] = vr;
            uint4 vc = *(const uint4*)((const char*)houtbase + (size_t)c * 512 + c16 * 16);
            *(uint4*)&featsB[e][FIN + c16 * 8] = vc;
        }
        if (q == 0) {
            rowlds[e] = r;
            const float cix = coord[(size_t)r*3+0], ciy = coord[(size_t)r*3+1], ciz = coord[(size_t)r*3+2];
            const float ckx = coord[(size_t)c*3+0], cky = coord[(size_t)c*3+1], ckz = coord[(size_t)c*3+2];
            const float dx = cix-ckx, dy = ciy-cky, dz = ciz-ckz;
            cdiff[e][0]=dx; cdiff[e][1]=dy; cdiff[e][2]=dz;
            const float radial = dx*dx + dy*dy + dz*dz;
            const float dist   = sqrtf(radial);
            const float dotv   = cix*ckx + ciy*cky + ciz*ckz;
            const float ia = 1.0f / (dist + 1e-8f);
            float ax = dx*ia, ay = dy*ia, az = dz*ia;
            const float cpx = ciy*ckz - ciz*cky;
            const float cpy = ciz*ckx - cix*ckz;
            const float cpz = cix*cky - ciy*ckx;
            const float cpn = sqrtf(cpx*cpx + cpy*cpy + cpz*cpz);
            const float ib = 1.0f / (cpn + 1e-8f);
            float bx = cpx*ib, by = cpy*ib, bz = cpz*ib;
            float cx = ay*bz - az*by;
            float cy = az*bx - ax*bz;
            float cz = ax*by - ay*bx;
            const float na = sqrtf(ax*ax + ay*ay + az*az);
            const float nb = sqrtf(bx*bx + by*by + bz*bz);
            const float nc = sqrtf(cx*cx + cy*cy + cz*cz);
            if (na < 1e-6f || nb < 1e-6f || nc < 1e-6f) {
                ax=1.f; bx=0.f; cx=0.f;
                ay=0.f; by=1.f; cy=0.f;
                az=0.f; bz=0.f; cz=1.f;
            }
            featsB[e][256]=(__bf16)radial; featsB[e][257]=(__bf16)dist; featsB[e][258]=(__bf16)dotv;
            featsB[e][259]=(__bf16)ax; featsB[e][260]=(__bf16)bx; featsB[e][261]=(__bf16)cx;
            featsB[e][262]=(__bf16)ay; featsB[e][263]=(__bf16)by; featsB[e][264]=(__bf16)cy;
            featsB[e][265]=(__bf16)az; featsB[e][266]=(__bf16)bz; featsB[e][267]=(__bf16)cz;
            #pragma unroll
            for (int k = FEATD; k < K1; k++) featsB[e][k] = (__bf16)0.f;
        }
    }
    __syncthreads();

    const int hh   = t >> 6;          // wave = head (GEMM1/2) / col-group (GEMM3)
    const int lane = t & 63;
    const int lr   = lane & 15;       // fragment row/col index
    const int lg   = lane >> 4;       // k-group (0..3)

    __bf16* hidB = ((__bf16*)smemB) + hh * (TE * 40);

    const f32x4 z4 = { 0.f, 0.f, 0.f, 0.f };

    // ---------------- GEMM1 (MFMA): feats[32x288] @ eW1t^T -> hid (own head) ----------------
    {
        f32x4 acc[2][2];
        #pragma unroll
        for (int mti = 0; mti < 2; mti++) { acc[mti][0] = z4; acc[mti][1] = z4; }
        const __bf16* W1 = eW1t + (size_t)hh * 32 * K1;
        #pragma unroll
        for (int ks = 0; ks < 9; ks++) {
            const int kof = ks * 32 + lg * 8;
            bf16x8 b0 = *(const bf16x8*)(W1 + (size_t)lr * K1 + kof);
            bf16x8 b1 = *(const bf16x8*)(W1 + (size_t)(16 + lr) * K1 + kof);
            #pragma unroll
            for (int mti = 0; mti < 2; mti++) {
                bf16x8 a = *(const bf16x8*)(&featsB[mti * 16 + lr][kof]);
                acc[mti][0] = MFMA(a, b0, acc[mti][0]);
                acc[mti][1] = MFMA(a, b1, acc[mti][1]);
            }
        }
        const float b1a = eb1[hh * HD + lr];
        const float b1b = eb1[hh * HD + 16 + lr];
        #pragma unroll
        for (int mti = 0; mti < 2; mti++) {
            #pragma unroll
            for (int r = 0; r < 4; r++) {
                const int erow = mti * 16 + lg * 4 + r;
                hidB[erow * 40 + lr]      = (__bf16)silu_f(acc[mti][0][r] + b1a);
                hidB[erow * 40 + 16 + lr] = (__bf16)silu_f(acc[mti][1][r] + b1b);
            }
        }
    }
    __syncthreads();

    // ---------------- GEMM2 (MFMA): hid @ eW2t^T + b2 -> efs (fp32) ----------------
    {
        f32x4 acc2[2][2];
        #pragma unroll
        for (int mti = 0; mti < 2; mti++) { acc2[mti][0] = z4; acc2[mti][1] = z4; }
        const __bf16* W2 = eW2t + (size_t)hh * HD * HD;
        const int kof2 = lg * 8;
        bf16x8 b20 = *(const bf16x8*)(W2 + (size_t)lr * HD + kof2);
        bf16x8 b21 = *(const bf16x8*)(W2 + (size_t)(16 + lr) * HD + kof2);
        #pragma unroll
        for (int mti = 0; mti < 2; mti++) {
            bf16x8 a = *(const bf16x8*)(hidB + (mti * 16 + lr) * 40 + kof2);
            acc2[mti][0] = MFMA(a, b20, acc2[mti][0]);
            acc2[mti][1] = MFMA(a, b21, acc2[mti][1]);
        }
        const float b2a = eb2[hh * HD + lr];
        const float b2b = eb2[hh * HD + 16 + lr];
        #pragma unroll
        for (int mti = 0; mti < 2; mti++) {
            #pragma unroll
            for (int r = 0; r < 4; r++) {
                const int erow = mti * 16 + lg * 4 + r;
                efs[erow][hh * HD + lr]      = acc2[mti][0][r] + b2a;
                efs[erow][hh * HD + 16 + lr] = acc2[mti][1][r] + b2b;
            }
        }
    }
    __syncthreads();

    // ---------------- LayerNorm over 128 (8 threads/edge) ----------------
    {
        const int el = t >> 3;
        const int q8 = t & 7;
        float s = 0.f, s2 = 0.f;
        #pragma unroll
        for (int i = 0; i < 16; i++) {
            const float v = efs[el][q8 + 8 * i];
            s += v; s2 += v * v;
        }
        s  += __shfl_xor(s, 1);  s  += __shfl_xor(s, 2);  s  += __shfl_xor(s, 4);
        s2 += __shfl_xor(s2, 1); s2 += __shfl_xor(s2, 2); s2 += __shfl_xor(s2, 4);
        const float mu   = s * (1.f / 128.f);
        const float var  = s2 * (1.f / 128.f) - mu * mu;
        const float rstd = rsqrtf(var + 1e-5f);
        #pragma unroll
        for (int i = 0; i < 16; i++) {
            const int oo = q8 + 8 * i;
            const float v  = efs[el][oo];
            const float nv = (v - mu) * rstd * ln_g[oo] + ln_b[oo];
            efsB[el][oo] = (__bf16)nv;
        }
    }
    __syncthreads();

    // ---------------- GEMM3 (MFMA): efsB @ cW1t^T -> silu -> *cW2 -> w per edge ----------------
    {
        f32x4 acc3[2][2];
        #pragma unroll
        for (int mti = 0; mti < 2; mti++) { acc3[mti][0] = z4; acc3[mti][1] = z4; }
        const __bf16* W3 = cW1t + (size_t)hh * 32 * HIDN;
        #pragma unroll
        for (int ks = 0; ks < 4; ks++) {
            const int kof = ks * 32 + lg * 8;
            bf16x8 b30 = *(const bf16x8*)(W3 + (size_t)lr * HIDN + kof);
            bf16x8 b31 = *(const bf16x8*)(W3 + (size_t)(16 + lr) * HIDN + kof);
            #pragma unroll
            for (int mti = 0; mti < 2; mti++) {
                bf16x8 a = *(const bf16x8*)(&efsB[mti * 16 + lr][kof]);
                acc3[mti][0] = MFMA(a, b30, acc3[mti][0]);
                acc3[mti][1] = MFMA(a, b31, acc3[mti][1]);
            }
        }
        const int c0 = hh * 32 + lr, c1 = c0 + 16;
        const float cbA = cb1[c0], cbB = cb1[c1];
        const float cwA = cW2[c0], cwB = cW2[c1];
        float pe[8];
        #pragma unroll
        for (int mti = 0; mti < 2; mti++)
            #pragma unroll
            for (int r = 0; r < 4; r++)
                pe[mti * 4 + r] = silu_f(acc3[mti][0][r] + cbA) * cwA
                                + silu_f(acc3[mti][1][r] + cbB) * cwB;
        #pragma unroll
        for (int d = 1; d < 16; d <<= 1)
            #pragma unroll
            for (int i = 0; i < 8; i++) pe[i] += __shfl_xor(pe[i], d);
        if (lr == 0) {
            #pragma unroll
            for (int mti = 0; mti < 2; mti++)
                #pragma unroll
                for (int r = 0; r < 4; r++)
                    atomicAdd(&wsum[mti * 16 + lg * 4 + r], pe[mti * 4 + r]);
        }
    }
    __syncthreads();

    // ---------------- coord scatter ----------------
    if (t < TE) {
        const float we = wsum[t];
        const int r = rowlds[t];
        atomicAdd(&coord_out[(size_t)r*3+0], cdiff[t][0] * we);
        atomicAdd(&coord_out[(size_t)r*3+1], cdiff[t][1] * we);
        atomicAdd(&coord_out[(size_t)r*3+2], cdiff[t][2] * we);
    }

    // ---------------- agg scatter: packed 2xbf16 atomics straight from efsB ----------------
    {
        const int p  = t & 63;           // feature-pair index (0..63)
        const int gq = t >> 6;           // 0..3
        #pragma unroll
        for (int e2 = 0; e2 < 8; e2++) {
            const int ee = gq * 8 + e2;
            __hip_bfloat162 pk = *(__hip_bfloat162*)&efsB[ee][2 * p];   // stride-1, no cvt
            __hip_bfloat162* addr = (__hip_bfloat162*)
                ((char*)houtbase + (size_t)rowlds[ee] * 512 + 256 + p * 4);
            unsafeAtomicAdd(addr, pk);
        }
    }
}

// 512 threads = 8 waves. Reads the full 512B h_out row = [hB bf16[128] | agg bf16[128]]
// = the 256-dim bf16 node-MLP input, then overwrites the row with final f32 h_out.
__global__ __launch_bounds__(512) void node_kernel(
    const float* __restrict__ h,
    const __bf16* __restrict__ nW1t, const float* __restrict__ nb1,
    const __bf16* __restrict__ nW2t, const float* __restrict__ nb2,
    float* __restrict__ h_out)
{
    __shared__ __align__(16) __bf16 featsN[TN2][264];   // [64][256+8]
    __shared__ __align__(16) __bf16 hidN[TN2][136];     // [64][128+8]

    const int t  = threadIdx.x;
    const int n0 = blockIdx.x * TN2;

    // ---------------- Phase 0: stage [hB | agg] row directly ----------------
    {
        const int n = t >> 3;
        const int q = t & 7;
        const int nid = n0 + n;
        const bool ok = nid < NN;
        const uint4* rowp = (const uint4*)((const char*)h_out + (size_t)nid * 512);
        #pragma unroll
        for (int j = 0; j < 4; j++) {
            const int w4 = q * 4 + j;                  // uint4 index 0..31
            uint4 u = ok ? rowp[w4] : make_uint4(0u, 0u, 0u, 0u);
            *(uint4*)&featsN[n][w4 * 8] = u;
        }
    }
    __syncthreads();

    const int wv2  = t >> 6;
    const int hh2  = wv2 >> 1;        // output col-group (0..3)
    const int mh   = wv2 & 1;         // node-half
    const int lane = t & 63;
    const int lr   = lane & 15;
    const int lg   = lane >> 4;

    const f32x4 z4 = { 0.f, 0.f, 0.f, 0.f };

    // ---------------- GEMM1n (MFMA): featsN[64x256] @ nW1t^T -> silu -> hidN ----------------
    {
        f32x4 acc[2][2];
        #pragma unroll
        for (int mti = 0; mti < 2; mti++) { acc[mti][0] = z4; acc[mti][1] = z4; }
        const __bf16* W1 = nW1t + (size_t)hh2 * 32 * 256;
        #pragma unroll
        for (int ks = 0; ks < 8; ks++) {
            const int kof = ks * 32 + lg * 8;
            bf16x8 b0 = *(const bf16x8*)(W1 + (size_t)lr * 256 + kof);
            bf16x8 b1 = *(const bf16x8*)(W1 + (size_t)(16 + lr) * 256 + kof);
            #pragma unroll
            for (int mti = 0; mti < 2; mti++) {
                bf16x8 a = *(const bf16x8*)(&featsN[(mh * 2 + mti) * 16 + lr][kof]);
                acc[mti][0] = MFMA(a, b0, acc[mti][0]);
                acc[mti][1] = MFMA(a, b1, acc[mti][1]);
            }
        }
        const float b1a = nb1[hh2 * 32 + lr];
        const float b1b = nb1[hh2 * 32 + 16 + lr];
        #pragma unroll
        for (int mti = 0; mti < 2; mti++) {
            #pragma unroll
            for (int r = 0; r < 4; r++) {
                const int erow = (mh * 2 + mti) * 16 + lg * 4 + r;
                hidN[erow][hh2 * 32 + lr]      = (__bf16)silu_f(acc[mti][0][r] + b1a);
                hidN[erow][hh2 * 32 + 16 + lr] = (__bf16)silu_f(acc[mti][1][r] + b1b);
            }
        }
    }
    __syncthreads();

    // ---------------- GEMM2n (MFMA): hidN[64x128] @ nW2t^T + nb2 + h -> h_out ----------------
    {
        f32x4 acc2[2][2];
        #pragma unroll
        for (int mti = 0; mti < 2; mti++) { acc2[mti][0] = z4; acc2[mti][1] = z4; }
        const __bf16* W2 = nW2t + (size_t)hh2 * 32 * 128;
        #pragma unroll
        for (int ks = 0; ks < 4; ks++) {
            const int kof = ks * 32 + lg * 8;
            bf16x8 b0 = *(const bf16x8*)(W2 + (size_t)lr * 128 + kof);
            bf16x8 b1 = *(const bf16x8*)(W2 + (size_t)(16 + lr) * 128 + kof);
            #pragma unroll
            for (int mti = 0; mti < 2; mti++) {
                bf16x8 a = *(const bf16x8*)(&hidN[(mh * 2 + mti) * 16 + lr][kof]);
                acc2[mti][0] = MFMA(a, b0, acc2[mti][0]);
                acc2[mti][1] = MFMA(a, b1, acc2[mti][1]);
            }
        }
        const float b2a = nb2[hh2 * 32 + lr];
        const float b2b = nb2[hh2 * 32 + 16 + lr];
        const int c0 = hh2 * 32 + lr, c1 = c0 + 16;
        #pragma unroll
        for (int mti = 0; mti < 2; mti++) {
            #pragma unroll
            for (int r = 0; r < 4; r++) {
                const int erow = (mh * 2 + mti) * 16 + lg * 4 + r;
                const int nid  = n0 + erow;
                if (nid < NN) {
                    h_out[(size_t)nid * FIN + c0] = h[(size_t)nid * FIN + c0] + acc2[mti][0][r] + b2a;
                    h_out[(size_t)nid * FIN + c1] = h[(size_t)nid * FIN + c1] + acc2[mti][1][r] + b2b;
                }
            }
        }
    }
}

extern "C" void kernel_launch(void* const* d_in, const int* in_sizes, int n_in,
                              void* d_out, int out_size, void* d_ws, size_t ws_size,
                              hipStream_t stream)
{
    (void)in_sizes; (void)n_in; (void)out_size; (void)ws_size;
    const float* h     = (const float*)d_in[0];
    const float* coord = (const float*)d_in[1];
    const int*   ei    = (const int*)d_in[2];
    const float* eW1   = (const float*)d_in[3];
    const float* eb1   = (const float*)d_in[4];
    const float* eW2   = (const float*)d_in[5];
    const float* eb2   = (const float*)d_in[6];
    const float* ln_g  = (const float*)d_in[7];
    const float* ln_b  = (const float*)d_in[8];
    const float* nW1   = (const float*)d_in[9];
    const float* nb1   = (const float*)d_in[10];
    const float* nW2   = (const float*)d_in[11];
    const float* nb2   = (const float*)d_in[12];
    const float* cW1   = (const float*)d_in[13];
    const float* cb1   = (const float*)d_in[14];
    const float* cW2   = (const float*)d_in[15];

    float* h_out     = (float*)d_out;
    float* coord_out = h_out + (size_t)NN * FIN;

    // bf16 transposed weights in ws
    __bf16* eW1t = (__bf16*)d_ws;               // 36864 elems
    __bf16* eW2t = eW1t + 4 * 32 * K1;          // 4096
    __bf16* cW1t = eW2t + 4 * HD * HD;          // 16384
    __bf16* nW1t = cW1t + HIDN * HIDN;          // 32768
    __bf16* nW2t = nW1t + HIDN * (2 * FIN);     // 16384  (total ~213KB of ws)

    // h_out row layout during edge phase: [hB bf16[128] | packed-bf16 agg[128]]
    hipMemsetAsync(h_out, 0, (size_t)NN * FIN * sizeof(float), stream);
    hipMemcpyAsync(coord_out, coord, (size_t)NN * 3 * sizeof(float),
                   hipMemcpyDeviceToDevice, stream);
    wconv_kernel<<<(4 * 32 * K1 + 255) / 256, 256, 0, stream>>>(
        eW1, eW2, cW1, nW1, nW2, eW1t, eW2t, cW1t, nW1t, nW2t);
    hconv_kernel<<<(NN * FIN / 8 + 255) / 256, 256, 0, stream>>>(h, h_out);

    edge_kernel<<<EE / TE, 256, 0, stream>>>(coord, ei, eW1t, eb1, eW2t, eb2,
                                             ln_g, ln_b, cW1t, cb1, cW2,
                                             h_out, coord_out);
    node_kernel<<<(NN + TN2 - 1) / TN2, 512, 0, stream>>>(h, nW1t, nb1, nW2t, nb2, h_out);
}